// Round 8
// baseline (478.531 us; speedup 1.0000x reference)
//
#include <hip/hip_runtime.h>
#include <math.h>

#define T_TOK 65536
#define K_CODE 1024
#define E_DIM 64
#define DECAYF 0.99f
#define EPSF 1e-5f

#define XREG 48           // x[0..47] in VGPRs
#define XLDS (64 - XREG)  // x[48..63] in LDS (transposed, conflict-free)
#define NWAVE 8           // waves per block (each scans 128 codes)

// --- exact-rounding helpers: block ffp-contract=fast fusion ---
__device__ __forceinline__ float mul_nf(float a, float b) {
#pragma clang fp contract(off)
    return a * b;
}
__device__ __forceinline__ float add_nf(float a, float b) {
#pragma clang fp contract(off)
    return a + b;
}
__device__ __forceinline__ float sub_nf(float a, float b) {
#pragma clang fp contract(off)
    return a - b;
}

// numpy pairwise_sum for n=64 of elementwise squares: products rounded
// separately (no fma), 8 strided accumulators, fixed combine tree.
__device__ __forceinline__ float np_sq_sum64(const float* v) {
    float r[8];
#pragma unroll
    for (int j = 0; j < 8; ++j) r[j] = mul_nf(v[j], v[j]);
#pragma unroll
    for (int i = 8; i < 64; i += 8) {
#pragma unroll
        for (int j = 0; j < 8; ++j) r[j] = add_nf(r[j], mul_nf(v[i + j], v[i + j]));
    }
    float s01 = add_nf(r[0], r[1]);
    float s23 = add_nf(r[2], r[3]);
    float s45 = add_nf(r[4], r[5]);
    float s67 = add_nf(r[6], r[7]);
    return add_nf(add_nf(s01, s23), add_nf(s45, s67));
}

// ws layout (floats):
// [0, 1024)        wnorm
// [1024]           diff accumulator
// [1025]           n (sum of new_cluster_size)
// [2048, 2048+8*1024)        onehot replicas
// [10240, 10240+8*65536)     embed_sum replicas

__global__ __launch_bounds__(256) void wnorm_kernel(const float* __restrict__ embed,
                                                    float* __restrict__ wnorm) {
    int k = blockIdx.x * 256 + threadIdx.x;
    if (k < K_CODE) {
        float w[64];
        const float4* wp = reinterpret_cast<const float4*>(embed + (size_t)k * E_DIM);
#pragma unroll
        for (int i = 0; i < 16; ++i) {
            float4 v = wp[i];
            w[4 * i + 0] = v.x; w[4 * i + 1] = v.y; w[4 * i + 2] = v.z; w[4 * i + 3] = v.w;
        }
        wnorm[k] = np_sq_sum64(w);
    }
}

// Block = 512 threads = 8 waves; 64 tokens/block (lane = token).
// Wave w scans code segment [w*128, (w+1)*128).
//   - x[0..47] in VGPRs, x[48..63] in LDS transposed (2 lanes/bank = free)
//   - w rows via wave-uniform pointers -> s_load, SGPR operand in the FMA
//   - k-unroll 4: each xl ds_read feeds 4 FMAs (round-7 showed the single
//     LDS pipe at 16 reads/2-codes was the limiter, not VALU)
//   - epilogue fuses the EMA scatter (wave W owns dims 8W..8W+7) so the
//     separate scatter kernel + its z_e re-read are deleted.
// Per-(token,code) arithmetic identical to the verified round-6/7 kernels
// (sequential i=0..63 FMA chain, same dist rounding, ascending-k strict-<,
// lower-segment-first combine) => bit-exact vs np reference.
__global__ __launch_bounds__(512) void argmin_kernel(const float* __restrict__ z_e,
                                                     const float* __restrict__ embed,
                                                     const float* __restrict__ wnorm,
                                                     float* __restrict__ out_zq,
                                                     float* __restrict__ out_ind,
                                                     float* __restrict__ diff_acc,
                                                     float* __restrict__ esum_rep,
                                                     float* __restrict__ onehot_rep,
                                                     int rep_mask) {
    __shared__ float xl[NWAVE][XLDS][64];  // 32 KB
    __shared__ float sd[NWAVE][64];        // 2 KB
    __shared__ int si[NWAVE][64];          // 2 KB
    __shared__ float sdiff[NWAVE];

    int lane = threadIdx.x & 63;
    int wave = threadIdx.x >> 6;
    int wseg = __builtin_amdgcn_readfirstlane(wave);  // provably uniform
    int t = blockIdx.x * 64 + lane;

    int rep = blockIdx.x & rep_mask;
    float* esum = esum_rep + (size_t)rep * (K_CODE * E_DIM);
    float* onehot = onehot_rep + (size_t)rep * K_CODE;

    // Load x: first XREG into registers, tail into LDS (transposed).
    // Simultaneously accumulate numpy-exact ||x||^2 (strided-8 pairwise).
    const float4* xp = reinterpret_cast<const float4*>(z_e + (size_t)t * E_DIM);
    float xr[XREG];
    float r[8];
#pragma unroll
    for (int g = 0; g < 8; ++g) {
        float4 va = xp[2 * g], vb = xp[2 * g + 1];
        float e[8] = {va.x, va.y, va.z, va.w, vb.x, vb.y, vb.z, vb.w};
#pragma unroll
        for (int j = 0; j < 8; ++j) {
            int i = 8 * g + j;
            if (g == 0) r[j] = mul_nf(e[j], e[j]);
            else        r[j] = add_nf(r[j], mul_nf(e[j], e[j]));
            if (i < XREG) xr[i] = e[j];
            else          xl[wave][i - XREG][lane] = e[j];
        }
    }
    float s01 = add_nf(r[0], r[1]);
    float s23 = add_nf(r[2], r[3]);
    float s45 = add_nf(r[4], r[5]);
    float s67 = add_nf(r[6], r[7]);
    float xn = add_nf(add_nf(s01, s23), add_nf(s45, s67));

    float best = INFINITY;
    int k0 = wseg << 7;
    int idx = k0;

    for (int k = k0; k < k0 + 128; k += 4) {
        const float* wr = embed + (size_t)k * E_DIM;  // uniform -> s_load
        float d0 = 0.f, d1 = 0.f, d2 = 0.f, d3 = 0.f;
#pragma unroll
        for (int i = 0; i < XREG; ++i) {
            float xv = xr[i];
            d0 = __builtin_fmaf(xv, wr[i], d0);
            d1 = __builtin_fmaf(xv, wr[E_DIM + i], d1);
            d2 = __builtin_fmaf(xv, wr[2 * E_DIM + i], d2);
            d3 = __builtin_fmaf(xv, wr[3 * E_DIM + i], d3);
        }
#pragma unroll
        for (int j = 0; j < XLDS; ++j) {
            float xv = xl[wave][j][lane];
            d0 = __builtin_fmaf(xv, wr[XREG + j], d0);
            d1 = __builtin_fmaf(xv, wr[E_DIM + XREG + j], d1);
            d2 = __builtin_fmaf(xv, wr[2 * E_DIM + XREG + j], d2);
            d3 = __builtin_fmaf(xv, wr[3 * E_DIM + XREG + j], d3);
        }
        float dist0 = add_nf(sub_nf(xn, d0 + d0), wnorm[k]);
        float dist1 = add_nf(sub_nf(xn, d1 + d1), wnorm[k + 1]);
        float dist2 = add_nf(sub_nf(xn, d2 + d2), wnorm[k + 2]);
        float dist3 = add_nf(sub_nf(xn, d3 + d3), wnorm[k + 3]);
        if (dist0 < best) { best = dist0; idx = k; }
        if (dist1 < best) { best = dist1; idx = k + 1; }
        if (dist2 < best) { best = dist2; idx = k + 2; }
        if (dist3 < best) { best = dist3; idx = k + 3; }
    }

    sd[wave][lane] = best;
    si[wave][lane] = idx;
    __syncthreads();

    // all waves: combine across segments (ascending => np first-min)
    float b = sd[0][lane];
    int bi = si[0][lane];
#pragma unroll
    for (int w = 1; w < NWAVE; ++w) {
        float d = sd[w][lane];
        int i2 = si[w][lane];
        if (d < b) { b = d; bi = i2; }
    }

    if (wave == 0) {
        out_ind[t] = (float)bi;
        atomicAdd(&onehot[bi], 1.0f);

        // z_q gather + straight-through output + diff partial
        // np order: r = fl(z_q - z_e); out = fl(z_e + r)
        const float4* wq = reinterpret_cast<const float4*>(embed + (size_t)bi * E_DIM);
        float4* oz = reinterpret_cast<float4*>(out_zq + (size_t)t * E_DIM);
        float ds = 0.f;
#pragma unroll
        for (int m = 0; m < 16; ++m) {
            float4 w4 = wq[m];
            float xv0, xv1, xv2, xv3;
            if (4 * m + 3 < XREG) {
                xv0 = xr[4 * m + 0]; xv1 = xr[4 * m + 1];
                xv2 = xr[4 * m + 2]; xv3 = xr[4 * m + 3];
            } else {
                xv0 = xl[0][4 * m + 0 - XREG][lane];
                xv1 = xl[0][4 * m + 1 - XREG][lane];
                xv2 = xl[0][4 * m + 2 - XREG][lane];
                xv3 = xl[0][4 * m + 3 - XREG][lane];
            }
            float rx = sub_nf(w4.x, xv0);
            float ry = sub_nf(w4.y, xv1);
            float rz = sub_nf(w4.z, xv2);
            float rw = sub_nf(w4.w, xv3);
            float4 o;
            o.x = add_nf(xv0, rx);
            o.y = add_nf(xv1, ry);
            o.z = add_nf(xv2, rz);
            o.w = add_nf(xv3, rw);
            oz[m] = o;
            ds = __builtin_fmaf(rx, rx, ds);
            ds = __builtin_fmaf(ry, ry, ds);
            ds = __builtin_fmaf(rz, rz, ds);
            ds = __builtin_fmaf(rw, rw, ds);
        }
#pragma unroll
        for (int o = 32; o > 0; o >>= 1) ds += __shfl_down(ds, o, 64);
        if (lane == 0) sdiff[0] = ds;
    }

    // fused EMA scatter: wave W owns dims [8W, 8W+8) for all 64 tokens.
    // Compile-time dim indices via wave-uniform branch (no dynamic xr index).
#pragma unroll
    for (int W = 0; W < NWAVE; ++W) {
        if (wseg == W) {
#pragma unroll
            for (int j = 0; j < 8; ++j) {
                const int dim = 8 * W + j;
                float xv = (dim < XREG) ? xr[dim < XREG ? dim : 0]
                                        : xl[W][(dim >= XREG) ? (dim - XREG) : 0][lane];
                atomicAdd(&esum[(size_t)bi * E_DIM + dim], xv);
            }
        }
    }

    __syncthreads();
    if (wave == 0 && lane == 0) atomicAdd(diff_acc, sdiff[0]);
}

// ncs, n, diff: single block (tiny)
__global__ __launch_bounds__(1024) void finalize_cs_kernel(const float* __restrict__ cluster_size,
                                                           const float* __restrict__ onehot_rep,
                                                           const float* __restrict__ ws_diff,
                                                           float* __restrict__ out_diff,
                                                           float* __restrict__ out_ncs,
                                                           float* __restrict__ ws_n,
                                                           int nrep) {
    int k = threadIdx.x;
    float oh = 0.f;
    for (int r = 0; r < nrep; ++r) oh += onehot_rep[(size_t)r * K_CODE + k];
    float ncs = DECAYF * cluster_size[k] + (1.0f - DECAYF) * oh;
    out_ncs[k] = ncs;

    __shared__ float red[1024];
    red[k] = ncs;
    __syncthreads();
#pragma unroll
    for (int s = 512; s > 0; s >>= 1) {
        if (k < s) red[k] += red[k + s];
        __syncthreads();
    }
    if (k == 0) {
        ws_n[0] = red[0];
        out_diff[0] = ws_diff[0] * (1.0f / 4194304.0f);  // /2^22 exact
    }
}

// embed_avg / embed update spread across 64 blocks
__global__ __launch_bounds__(256) void finalize_embed_kernel(const float* __restrict__ embed_avg,
                                                             const float* __restrict__ esum_rep,
                                                             const float* __restrict__ out_ncs,
                                                             const float* __restrict__ ws_n,
                                                             float* __restrict__ out_ne,
                                                             float* __restrict__ out_nea,
                                                             int nrep) {
    int gid = blockIdx.x * 256 + threadIdx.x;
    int k = gid >> 4;        // row
    int c = gid & 15;        // float4 chunk
    float n = ws_n[0];
    float ncs = out_ncs[k];
    float cs = (ncs + EPSF) / (n + (float)K_CODE * EPSF) * n;

    size_t off = (size_t)k * E_DIM + (size_t)c * 4;
    float4 s4 = make_float4(0.f, 0.f, 0.f, 0.f);
    for (int r = 0; r < nrep; ++r) {
        float4 v = *reinterpret_cast<const float4*>(esum_rep + (size_t)r * (K_CODE * E_DIM) + off);
        s4.x += v.x; s4.y += v.y; s4.z += v.z; s4.w += v.w;
    }
    float4 a = *reinterpret_cast<const float4*>(embed_avg + off);
    float4 nea, ne;
    nea.x = DECAYF * a.x + (1.0f - DECAYF) * s4.x;
    nea.y = DECAYF * a.y + (1.0f - DECAYF) * s4.y;
    nea.z = DECAYF * a.z + (1.0f - DECAYF) * s4.z;
    nea.w = DECAYF * a.w + (1.0f - DECAYF) * s4.w;
    ne.x = nea.x / cs; ne.y = nea.y / cs; ne.z = nea.z / cs; ne.w = nea.w / cs;
    *reinterpret_cast<float4*>(out_nea + off) = nea;
    *reinterpret_cast<float4*>(out_ne + off) = ne;
}

extern "C" void kernel_launch(void* const* d_in, const int* in_sizes, int n_in,
                              void* d_out, int out_size, void* d_ws, size_t ws_size,
                              hipStream_t stream) {
    const float* z_e = (const float*)d_in[0];
    const float* embed = (const float*)d_in[1];
    const float* cluster_size = (const float*)d_in[2];
    const float* embed_avg = (const float*)d_in[3];

    float* out = (float*)d_out;
    float* o_zq = out;                   // 4194304
    float* o_diff = out + 4194304;       // 1
    float* o_ind = out + 4194305;        // 65536
    float* o_ne = out + 4194305 + 65536; // 65536
    float* o_ncs = o_ne + 65536;         // 1024
    float* o_nea = o_ncs + 1024;         // 65536

    float* ws = (float*)d_ws;
    float* ws_wnorm = ws;            // [0,1024)
    float* ws_diff = ws + 1024;      // [1024]
    float* ws_n = ws + 1025;         // [1025]
    float* ws_onehot = ws + 2048;    // nrep*1024
    float* ws_esum = ws + 10240;     // nrep*65536

    // choose replica count by available workspace
    int nrep = 1;
    while (nrep < 8 && ws_size >= (size_t)(10240 + (size_t)(nrep * 2) * 65536) * 4) nrep *= 2;

    size_t clear_floats = 10240 + (size_t)nrep * 65536;
    hipMemsetAsync(d_ws, 0, clear_floats * sizeof(float), stream);
    wnorm_kernel<<<4, 256, 0, stream>>>(embed, ws_wnorm);
    argmin_kernel<<<1024, 512, 0, stream>>>(z_e, embed, ws_wnorm, o_zq, o_ind, ws_diff,
                                            ws_esum, ws_onehot, nrep - 1);
    finalize_cs_kernel<<<1, 1024, 0, stream>>>(cluster_size, ws_onehot, ws_diff,
                                               o_diff, o_ncs, ws_n, nrep);
    finalize_embed_kernel<<<64, 256, 0, stream>>>(embed_avg, ws_esum, o_ncs, ws_n,
                                                  o_ne, o_nea, nrep);
}

// Round 9
// 246.645 us; speedup vs baseline: 1.9402x; 1.9402x over previous
//
#include <hip/hip_runtime.h>
#include <math.h>

#define T_TOK 65536
#define K_CODE 1024
#define E_DIM 64
#define DECAYF 0.99f
#define EPSF 1e-5f

#define XREG 44           // x[0..43] in VGPRs (fits 64-VGPR budget w/ unroll-4)
#define XLDS (64 - XREG)  // x[44..63] in shared LDS (transposed, conflict-free)
#define NWAVE 8           // waves per block (each scans 128 codes)

// --- exact-rounding helpers: block ffp-contract=fast fusion ---
__device__ __forceinline__ float mul_nf(float a, float b) {
#pragma clang fp contract(off)
    return a * b;
}
__device__ __forceinline__ float add_nf(float a, float b) {
#pragma clang fp contract(off)
    return a + b;
}
__device__ __forceinline__ float sub_nf(float a, float b) {
#pragma clang fp contract(off)
    return a - b;
}

// numpy pairwise_sum for n=64 of elementwise squares: products rounded
// separately (no fma), 8 strided accumulators, fixed combine tree.
__device__ __forceinline__ float np_sq_sum64(const float* v) {
    float r[8];
#pragma unroll
    for (int j = 0; j < 8; ++j) r[j] = mul_nf(v[j], v[j]);
#pragma unroll
    for (int i = 8; i < 64; i += 8) {
#pragma unroll
        for (int j = 0; j < 8; ++j) r[j] = add_nf(r[j], mul_nf(v[i + j], v[i + j]));
    }
    float s01 = add_nf(r[0], r[1]);
    float s23 = add_nf(r[2], r[3]);
    float s45 = add_nf(r[4], r[5]);
    float s67 = add_nf(r[6], r[7]);
    return add_nf(add_nf(s01, s23), add_nf(s45, s67));
}

// ws layout (floats):
// [0, 1024)        wnorm
// [1024]           diff accumulator
// [1025]           n (sum of new_cluster_size)
// [2048, 2048+8*1024)        onehot replicas
// [10240, 10240+8*65536)     embed_sum replicas

__global__ __launch_bounds__(256) void wnorm_kernel(const float* __restrict__ embed,
                                                    float* __restrict__ wnorm) {
    int k = blockIdx.x * 256 + threadIdx.x;
    if (k < K_CODE) {
        float w[64];
        const float4* wp = reinterpret_cast<const float4*>(embed + (size_t)k * E_DIM);
#pragma unroll
        for (int i = 0; i < 16; ++i) {
            float4 v = wp[i];
            w[4 * i + 0] = v.x; w[4 * i + 1] = v.y; w[4 * i + 2] = v.z; w[4 * i + 3] = v.w;
        }
        wnorm[k] = np_sq_sum64(w);
    }
}

// Block = 512 threads = 8 waves; 64 tokens/block (lane = token).
// Wave w scans code segment [w*128, (w+1)*128), k-unroll 4.
//   - x[0..43] in VGPRs; x[44..63] in ONE shared xl[XLDS][64] (wave 0 writes,
//     one barrier) - identical values for all waves, 5 KB instead of 8 copies
//   - xt[64][65] padded transpose (wave 0 writes) enables the fused scatter
//     to read lane=dim conflict-free -> COALESCED 256B row atomics (round-8's
//     149 MB writeback came from lane=token scattered atomics)
//   - w rows via wave-uniform pointers -> s_load, SGPR operand in the FMA
// Per-(token,code) arithmetic identical to verified round-6/7 kernels
// (sequential i=0..63 FMA chain, same dist rounding, ascending-k strict-<,
// lower-segment-first combine) => bit-exact vs np reference.
__global__ __launch_bounds__(512) void argmin_kernel(const float* __restrict__ z_e,
                                                     const float* __restrict__ embed,
                                                     const float* __restrict__ wnorm,
                                                     float* __restrict__ out_zq,
                                                     float* __restrict__ out_ind,
                                                     float* __restrict__ diff_acc,
                                                     float* __restrict__ esum_rep,
                                                     float* __restrict__ onehot_rep,
                                                     int rep_mask) {
    __shared__ float xl[XLDS][64];   // 5 KB   tail dims, [dim-XREG][token]
    __shared__ float xt[64][65];     // 16.6 KB full transpose [dim][token], padded
    __shared__ float sd[NWAVE][64];  // 2 KB
    __shared__ int si[NWAVE][64];    // 2 KB
    __shared__ int s_bi[64];         // 256 B  final argmin per token

    int lane = threadIdx.x & 63;
    int wave = threadIdx.x >> 6;
    int wseg = __builtin_amdgcn_readfirstlane(wave);  // provably uniform
    int t = blockIdx.x * 64 + lane;

    int rep = blockIdx.x & rep_mask;
    float* esum = esum_rep + (size_t)rep * (K_CODE * E_DIM);
    float* onehot = onehot_rep + (size_t)rep * K_CODE;

    // Load x (all waves load the same 64 tokens; L1 absorbs the redundancy).
    // Wave 0 additionally publishes the LDS tail + full transpose.
    // Simultaneously accumulate numpy-exact ||x||^2 (strided-8 pairwise).
    const float4* xp = reinterpret_cast<const float4*>(z_e + (size_t)t * E_DIM);
    float xr[XREG];
    float r[8];
#pragma unroll
    for (int g = 0; g < 8; ++g) {
        float4 va = xp[2 * g], vb = xp[2 * g + 1];
        float e[8] = {va.x, va.y, va.z, va.w, vb.x, vb.y, vb.z, vb.w};
#pragma unroll
        for (int j = 0; j < 8; ++j) {
            int i = 8 * g + j;
            if (g == 0) r[j] = mul_nf(e[j], e[j]);
            else        r[j] = add_nf(r[j], mul_nf(e[j], e[j]));
            if (i < XREG) xr[i] = e[j];
            if (wave == 0) {
                if (i >= XREG) xl[i - XREG][lane] = e[j];
                xt[i][lane] = e[j];  // (i+lane)%32 banks -> 2 lanes/bank, free
            }
        }
    }
    float s01 = add_nf(r[0], r[1]);
    float s23 = add_nf(r[2], r[3]);
    float s45 = add_nf(r[4], r[5]);
    float s67 = add_nf(r[6], r[7]);
    float xn = add_nf(add_nf(s01, s23), add_nf(s45, s67));

    __syncthreads();  // xl / xt visible to all waves

    float best = INFINITY;
    int k0 = wseg << 7;
    int idx = k0;

    for (int k = k0; k < k0 + 128; k += 4) {
        const float* wr = embed + (size_t)k * E_DIM;  // uniform -> s_load
        float d0 = 0.f, d1 = 0.f, d2 = 0.f, d3 = 0.f;
#pragma unroll
        for (int i = 0; i < XREG; ++i) {
            float xv = xr[i];
            d0 = __builtin_fmaf(xv, wr[i], d0);
            d1 = __builtin_fmaf(xv, wr[E_DIM + i], d1);
            d2 = __builtin_fmaf(xv, wr[2 * E_DIM + i], d2);
            d3 = __builtin_fmaf(xv, wr[3 * E_DIM + i], d3);
        }
#pragma unroll
        for (int j = 0; j < XLDS; ++j) {
            float xv = xl[j][lane];
            d0 = __builtin_fmaf(xv, wr[XREG + j], d0);
            d1 = __builtin_fmaf(xv, wr[E_DIM + XREG + j], d1);
            d2 = __builtin_fmaf(xv, wr[2 * E_DIM + XREG + j], d2);
            d3 = __builtin_fmaf(xv, wr[3 * E_DIM + XREG + j], d3);
        }
        float dist0 = add_nf(sub_nf(xn, d0 + d0), wnorm[k]);
        float dist1 = add_nf(sub_nf(xn, d1 + d1), wnorm[k + 1]);
        float dist2 = add_nf(sub_nf(xn, d2 + d2), wnorm[k + 2]);
        float dist3 = add_nf(sub_nf(xn, d3 + d3), wnorm[k + 3]);
        if (dist0 < best) { best = dist0; idx = k; }
        if (dist1 < best) { best = dist1; idx = k + 1; }
        if (dist2 < best) { best = dist2; idx = k + 2; }
        if (dist3 < best) { best = dist3; idx = k + 3; }
    }

    sd[wave][lane] = best;
    si[wave][lane] = idx;
    __syncthreads();

    if (wave == 0) {
        // combine across segments (ascending => np first-min)
        float b = sd[0][lane];
        int bi = si[0][lane];
#pragma unroll
        for (int w = 1; w < NWAVE; ++w) {
            float d = sd[w][lane];
            int i2 = si[w][lane];
            if (d < b) { b = d; bi = i2; }
        }
        s_bi[lane] = bi;
        out_ind[t] = (float)bi;

        // z_q gather + straight-through output + diff partial
        // np order: r = fl(z_q - z_e); out = fl(z_e + r)
        const float4* wq = reinterpret_cast<const float4*>(embed + (size_t)bi * E_DIM);
        float4* oz = reinterpret_cast<float4*>(out_zq + (size_t)t * E_DIM);
        float ds = 0.f;
#pragma unroll
        for (int m = 0; m < 16; ++m) {
            float4 w4 = wq[m];
            float xv0, xv1, xv2, xv3;
            if (4 * m + 3 < XREG) {
                xv0 = xr[4 * m + 0]; xv1 = xr[4 * m + 1];
                xv2 = xr[4 * m + 2]; xv3 = xr[4 * m + 3];
            } else {
                xv0 = xl[4 * m + 0 - XREG][lane];
                xv1 = xl[4 * m + 1 - XREG][lane];
                xv2 = xl[4 * m + 2 - XREG][lane];
                xv3 = xl[4 * m + 3 - XREG][lane];
            }
            float rx = sub_nf(w4.x, xv0);
            float ry = sub_nf(w4.y, xv1);
            float rz = sub_nf(w4.z, xv2);
            float rw = sub_nf(w4.w, xv3);
            float4 o;
            o.x = add_nf(xv0, rx);
            o.y = add_nf(xv1, ry);
            o.z = add_nf(xv2, rz);
            o.w = add_nf(xv3, rw);
            oz[m] = o;
            ds = __builtin_fmaf(rx, rx, ds);
            ds = __builtin_fmaf(ry, ry, ds);
            ds = __builtin_fmaf(rz, rz, ds);
            ds = __builtin_fmaf(rw, rw, ds);
        }
#pragma unroll
        for (int o = 32; o > 0; o >>= 1) ds += __shfl_down(ds, o, 64);
        if (lane == 0) atomicAdd(diff_acc, ds);
    }

    __syncthreads();  // s_bi visible

    // fused EMA scatter, COALESCED: wave W owns tokens [8W, 8W+8), lane = dim.
    // xt[lane][tl]: banks (lane+tl)%32 -> 2 lanes/bank, free. One 256B
    // row-atomic per token (same traffic shape as the fast round-7 scatter).
#pragma unroll
    for (int j = 0; j < 8; ++j) {
        int tl = (wseg << 3) + j;
        int bi2 = s_bi[tl];  // broadcast read
        float xv = xt[lane][tl];
        atomicAdd(&esum[(size_t)bi2 * E_DIM + lane], xv);
        if (lane == 0) atomicAdd(&onehot[bi2], 1.0f);
    }
}

// ncs, n, diff: single block (tiny)
__global__ __launch_bounds__(1024) void finalize_cs_kernel(const float* __restrict__ cluster_size,
                                                           const float* __restrict__ onehot_rep,
                                                           const float* __restrict__ ws_diff,
                                                           float* __restrict__ out_diff,
                                                           float* __restrict__ out_ncs,
                                                           float* __restrict__ ws_n,
                                                           int nrep) {
    int k = threadIdx.x;
    float oh = 0.f;
    for (int r = 0; r < nrep; ++r) oh += onehot_rep[(size_t)r * K_CODE + k];
    float ncs = DECAYF * cluster_size[k] + (1.0f - DECAYF) * oh;
    out_ncs[k] = ncs;

    __shared__ float red[1024];
    red[k] = ncs;
    __syncthreads();
#pragma unroll
    for (int s = 512; s > 0; s >>= 1) {
        if (k < s) red[k] += red[k + s];
        __syncthreads();
    }
    if (k == 0) {
        ws_n[0] = red[0];
        out_diff[0] = ws_diff[0] * (1.0f / 4194304.0f);  // /2^22 exact
    }
}

// embed_avg / embed update spread across 64 blocks
__global__ __launch_bounds__(256) void finalize_embed_kernel(const float* __restrict__ embed_avg,
                                                             const float* __restrict__ esum_rep,
                                                             const float* __restrict__ out_ncs,
                                                             const float* __restrict__ ws_n,
                                                             float* __restrict__ out_ne,
                                                             float* __restrict__ out_nea,
                                                             int nrep) {
    int gid = blockIdx.x * 256 + threadIdx.x;
    int k = gid >> 4;        // row
    int c = gid & 15;        // float4 chunk
    float n = ws_n[0];
    float ncs = out_ncs[k];
    float cs = (ncs + EPSF) / (n + (float)K_CODE * EPSF) * n;

    size_t off = (size_t)k * E_DIM + (size_t)c * 4;
    float4 s4 = make_float4(0.f, 0.f, 0.f, 0.f);
    for (int r = 0; r < nrep; ++r) {
        float4 v = *reinterpret_cast<const float4*>(esum_rep + (size_t)r * (K_CODE * E_DIM) + off);
        s4.x += v.x; s4.y += v.y; s4.z += v.z; s4.w += v.w;
    }
    float4 a = *reinterpret_cast<const float4*>(embed_avg + off);
    float4 nea, ne;
    nea.x = DECAYF * a.x + (1.0f - DECAYF) * s4.x;
    nea.y = DECAYF * a.y + (1.0f - DECAYF) * s4.y;
    nea.z = DECAYF * a.z + (1.0f - DECAYF) * s4.z;
    nea.w = DECAYF * a.w + (1.0f - DECAYF) * s4.w;
    ne.x = nea.x / cs; ne.y = nea.y / cs; ne.z = nea.z / cs; ne.w = nea.w / cs;
    *reinterpret_cast<float4*>(out_nea + off) = nea;
    *reinterpret_cast<float4*>(out_ne + off) = ne;
}

extern "C" void kernel_launch(void* const* d_in, const int* in_sizes, int n_in,
                              void* d_out, int out_size, void* d_ws, size_t ws_size,
                              hipStream_t stream) {
    const float* z_e = (const float*)d_in[0];
    const float* embed = (const float*)d_in[1];
    const float* cluster_size = (const float*)d_in[2];
    const float* embed_avg = (const float*)d_in[3];

    float* out = (float*)d_out;
    float* o_zq = out;                   // 4194304
    float* o_diff = out + 4194304;       // 1
    float* o_ind = out + 4194305;        // 65536
    float* o_ne = out + 4194305 + 65536; // 65536
    float* o_ncs = o_ne + 65536;         // 1024
    float* o_nea = o_ncs + 1024;         // 65536

    float* ws = (float*)d_ws;
    float* ws_wnorm = ws;            // [0,1024)
    float* ws_diff = ws + 1024;      // [1024]
    float* ws_n = ws + 1025;         // [1025]
    float* ws_onehot = ws + 2048;    // nrep*1024
    float* ws_esum = ws + 10240;     // nrep*65536

    // choose replica count by available workspace
    int nrep = 1;
    while (nrep < 8 && ws_size >= (size_t)(10240 + (size_t)(nrep * 2) * 65536) * 4) nrep *= 2;

    size_t clear_floats = 10240 + (size_t)nrep * 65536;
    hipMemsetAsync(d_ws, 0, clear_floats * sizeof(float), stream);
    wnorm_kernel<<<4, 256, 0, stream>>>(embed, ws_wnorm);
    argmin_kernel<<<1024, 512, 0, stream>>>(z_e, embed, ws_wnorm, o_zq, o_ind, ws_diff,
                                            ws_esum, ws_onehot, nrep - 1);
    finalize_cs_kernel<<<1, 1024, 0, stream>>>(cluster_size, ws_onehot, ws_diff,
                                               o_diff, o_ncs, ws_n, nrep);
    finalize_embed_kernel<<<64, 256, 0, stream>>>(embed_avg, ws_esum, o_ncs, ws_n,
                                                  o_ne, o_nea, nrep);
}